// Round 11
// baseline (201.327 us; speedup 1.0000x reference)
//
#include <hip/hip_runtime.h>
#include <hip/hip_bf16.h>

#define B_SZ 8192
#define D_SZ 1024   // elements; == bytes in fp8

typedef __attribute__((ext_vector_type(4))) float floatx4;
typedef __attribute__((ext_vector_type(8))) int   int8v;
typedef __attribute__((ext_vector_type(4))) int   int4v;

// ---------------------------------------------------------------------------
// Tiled fp8 operand layout ("MFMA order"): the matrix is stored as
// 2 KB tiles, one per (16-row panel p, 128-byte K-chunk c):
//   tile_base = (p*8 + c) * 2048
//   byte (lane*32 + j) of the tile = row (p*16 + (lane&15)),
//                                    K-byte (c*128 + (lane>>4)*32 + j)
// A fragment load for mfma_scale_f32_16x16x128 (lane l16=row, quad=K-chunk)
// is then exactly bytes lane*32..+31 of one tile: two coalesced dwordx4.
// ---------------------------------------------------------------------------

// One block per 16-row panel (1024 blocks: 512 img + 512 txt).
// Phase 1: 256 threads load the panel (fp32), per-row sum-squares via
// 16-lane shuffle groups. Phase 2: pack fp8 to LDS row-linear, then emit
// the 8 tiles in MFMA order with fully-coalesced 16 B stores.
__global__ __launch_bounds__(256) void norm_cast_fp8t(
    const float* __restrict__ img, const float* __restrict__ txt,
    unsigned char* __restrict__ imgT, unsigned char* __restrict__ txtT,
    float* __restrict__ out)
{
    if (blockIdx.x == 0 && threadIdx.x == 0) *out = 0.0f;   // stream-ordered init

    int b = blockIdx.x;
    const float* src; unsigned char* dst;
    if (b < B_SZ / 16) { src = img + (size_t)b * 16 * D_SZ; dst = imgT + (size_t)b * 16 * D_SZ; }
    else { b -= B_SZ / 16; src = txt + (size_t)b * 16 * D_SZ; dst = txtT + (size_t)b * 16 * D_SZ; }

    const int t = threadIdx.x;
    const int r = t >> 4;          // row 0..15 within panel
    const int m = t & 15;          // 16 threads cooperate on one row

    // row r, elements 4m+64j .. +3  (float4 index r*256 + m + 16j)
    float4 v[16];
    float ss = 0.0f;
    #pragma unroll
    for (int j = 0; j < 16; ++j) {
        v[j] = ((const float4*)src)[r * 256 + m + 16 * j];
        ss += v[j].x*v[j].x + v[j].y*v[j].y + v[j].z*v[j].z + v[j].w*v[j].w;
    }
    #pragma unroll
    for (int off = 1; off < 16; off <<= 1) ss += __shfl_xor(ss, off, 64);
    const float scale = 1.0f / fmaxf(sqrtf(ss), 1e-12f);

    __shared__ unsigned char P[16 * 1024];    // panel, fp8, row-linear
    #pragma unroll
    for (int j = 0; j < 16; ++j) {
        int packed = 0;
        packed = __builtin_amdgcn_cvt_pk_fp8_f32(v[j].x * scale, v[j].y * scale, packed, false);
        packed = __builtin_amdgcn_cvt_pk_fp8_f32(v[j].z * scale, v[j].w * scale, packed, true);
        *(int*)(P + r * 1024 + m * 4 + 64 * j) = packed;
    }
    __syncthreads();

    // emit tiles: thread t -> tile c = t>>5, lane-slots s and s+32 (s = t&31)
    const int c = t >> 5, s = t & 31;
    #pragma unroll
    for (int h = 0; h < 2; ++h) {
        const int sl = s + h * 32;
        const int l16 = sl & 15, quad = sl >> 4;
        const unsigned char* p_ = P + l16 * 1024 + c * 128 + quad * 32;
        int4v w0 = *(const int4v*)(p_);
        int4v w1 = *(const int4v*)(p_ + 16);
        unsigned char* gp = dst + c * 2048 + sl * 32;
        *(int4v*)(gp)      = w0;
        *(int4v*)(gp + 16) = w1;
    }
}

// Fused MX-fp8 GEMM (A @ B^T) + SigLIP loss — NO LDS, NO K-loop barriers.
// 128x128 block tile, 4 waves 2x2, wave tile 64x64 (4x4 of 16x16x128
// scaled-MFMA, scales = 1.0), 8 K-iters. Operands are pre-tiled in MFMA
// order, so every fragment is two coalesced global_load_dwordx4 straight
// into the MFMA input registers. With no __syncthreads in the loop there is
// no vmcnt(0) drain: the compiler schedules loads across iterations with
// fine-grained vmcnt (the hipBLASLt-style pipeline the LDS structure
// couldn't express). Working set 16 MB = L2/L3-resident; consecutive
// blockIdx.x share bj so XCD-resident blocks reuse B tiles in L2.
__global__ __launch_bounds__(256, 2) void siglip_gemm_loss_fp8(
    const unsigned char* __restrict__ A,   // imgT, tiled
    const unsigned char* __restrict__ Bt,  // txtT, tiled
    const float* __restrict__ tp, const float* __restrict__ bp,
    float* __restrict__ out)
{
    const int tid  = threadIdx.x;
    const int lane = tid & 63;
    const int wave = tid >> 6;
    const int wm = wave & 1, wn = wave >> 1;
    const int bi = blockIdx.x * 128;
    const int bj = blockIdx.y * 128;
    const int quad = lane >> 4;
    const int l16  = lane & 15;

    floatx4 acc[4][4];
    #pragma unroll
    for (int i = 0; i < 4; ++i)
        #pragma unroll
        for (int j = 0; j < 4; ++j)
            acc[i][j] = (floatx4){0.f, 0.f, 0.f, 0.f};

    // wave's base: panel (bi/16 + wm*4 + mt), tile offset = panel*8*2048
    const unsigned char* Ab = A  + (unsigned)((bi >> 4) + wm * 4) * 16384 + lane * 32;
    const unsigned char* Bb = Bt + (unsigned)((bj >> 4) + wn * 4) * 16384 + lane * 32;

    union frag { int8v v8; struct { int4v lo, hi; } s; };

    #pragma unroll
    for (int kk = 0; kk < D_SZ / 128; ++kk) {
        frag af[4], bf[4];
        #pragma unroll
        for (int mt = 0; mt < 4; ++mt) {
            const unsigned char* ap = Ab + mt * 16384 + kk * 2048;
            af[mt].s.lo = *(const int4v*)(ap);
            af[mt].s.hi = *(const int4v*)(ap + 16);
        }
        #pragma unroll
        for (int nt = 0; nt < 4; ++nt) {
            const unsigned char* bp_ = Bb + nt * 16384 + kk * 2048;
            bf[nt].s.lo = *(const int4v*)(bp_);
            bf[nt].s.hi = *(const int4v*)(bp_ + 16);
        }
        #pragma unroll
        for (int mt = 0; mt < 4; ++mt)
            #pragma unroll
            for (int nt = 0; nt < 4; ++nt)
                acc[mt][nt] = __builtin_amdgcn_mfma_scale_f32_16x16x128_f8f6f4(
                    af[mt].v8, bf[nt].v8, acc[mt][nt],
                    0, 0,          // cbsz=fp8, blgp=fp8
                    0, 127,        // scale A: E8M0 127 = 1.0
                    0, 127);       // scale B
    }

    // Epilogue: softplus(-label*logit) with hw exp/log, reduce.
    const float t    = fminf(__expf(tp[0]), 100.0f);
    const float bias = bp[0];
    float lsum = 0.0f;
    #pragma unroll
    for (int mt = 0; mt < 4; ++mt) {
        #pragma unroll
        for (int nt = 0; nt < 4; ++nt) {
            const int jj = bj + wn * 64 + nt * 16 + l16;              // C/D col
            #pragma unroll
            for (int r = 0; r < 4; ++r) {
                const int ii = bi + wm * 64 + mt * 16 + quad * 4 + r; // C/D row
                float logit = fmaf(acc[mt][nt][r], t, bias);
                float z = (ii == jj) ? logit : -logit;
                float e = __expf(-fabsf(z));
                lsum += fmaxf(-z, 0.0f) + __logf(1.0f + e);
            }
        }
    }
    #pragma unroll
    for (int off = 32; off > 0; off >>= 1) lsum += __shfl_down(lsum, off, 64);

    __shared__ float red[4];
    if (lane == 0) red[wave] = lsum;
    __syncthreads();
    if (tid == 0)
        atomicAdd(out, (red[0] + red[1] + red[2] + red[3]) * (1.0f / (float)B_SZ));
}

extern "C" void kernel_launch(void* const* d_in, const int* in_sizes, int n_in,
                              void* d_out, int out_size, void* d_ws, size_t ws_size,
                              hipStream_t stream) {
    const float* img = (const float*)d_in[0];
    const float* txt = (const float*)d_in[1];
    const float* tp  = (const float*)d_in[2];
    const float* bp  = (const float*)d_in[3];
    float* out = (float*)d_out;

    unsigned char* imgT = (unsigned char*)d_ws;                   // 8 MB, tiled
    unsigned char* txtT = imgT + (size_t)B_SZ * D_SZ;             // 8 MB, tiled

    norm_cast_fp8t<<<2 * (B_SZ / 16), 256, 0, stream>>>(img, txt, imgT, txtT, out);
    dim3 grid(B_SZ / 128, B_SZ / 128);
    siglip_gemm_loss_fp8<<<grid, 256, 0, stream>>>(imgT, txtT, tp, bp, out);
}